// Round 6
// baseline (92.191 us; speedup 1.0000x reference)
//
#include <hip/hip_runtime.h>
#include <hip/hip_bf16.h>

// PartiallyExchangeableNetwork on MI355X (gfx950)
// N=256, M=3, T=4096, ORDER=2 -> L=4094 windows, H=128, OUT=10
//
// h1 = relu(xin @ W1 + b1); h2 = relu(h1 @ W2 + b2); colsum over L.
// Layer 3 folded through the sum: sum_l(h2@W3+b3) = (sum_l h2)@W3 + L*b3 (tail kernel).
//
// R6 structure: 2x2 wave grid per 64-row step. Wave (wr,wc) owns rows
// [32wr,32wr+32) x channels/outputs [64wc,64wc+64). Halves h1s read traffic
// (each wave reads only its 32 rows) and xw reads vs the 1x4 o-split.
// h1s double-buffered -> 1 barrier/step. Swizzle: c' = c ^ ((r&15)<<3).

#define NN 256
#define MM 3
#define TT 4096
#define LL 4094
#define HH 128
#define CHUNKS 8
#define RPC 512          // rows (windows) per chunk (2 halves of 256)
#define RPH 256          // rows per staged half
#define HALVES 2
#define STEPS 4          // 64-row steps per half
#define SR 64            // rows per step (block tile)
#define XROW 24          // xw row stride in halfwords (48 B)

typedef __attribute__((ext_vector_type(8))) short bf16x8;
typedef __attribute__((ext_vector_type(4))) float f32x4;
typedef __attribute__((ext_vector_type(4))) unsigned short u16x4;
typedef __attribute__((ext_vector_type(2))) unsigned int u32x2;

__device__ __forceinline__ unsigned short f2bf(float x) {
    __hip_bfloat16 h = __float2bfloat16(x);           // RNE, hw cvt on gfx950
    union { __hip_bfloat16 h; unsigned short u; } v; v.h = h;
    return v.u;
}

__global__ __launch_bounds__(256, 2) void pen_inner(
    const float* __restrict__ x,
    const float* __restrict__ w1, const float* __restrict__ b1,
    const float* __restrict__ w2, const float* __restrict__ b2,
    float* __restrict__ partials)
{
    __shared__ __align__(16) unsigned short xw[XROW * (RPH + 1) + 8]; // 12.4 KB
    __shared__ __align__(16) unsigned short h1s[2][SR * HH];          // 32.8 KB dbuf
    __shared__ float red[2][HH];                                      // 1 KB

    const int tid  = threadIdx.x;
    const int wave = tid >> 6;
    const int lane = tid & 63;
    const int lr   = lane & 15;   // MFMA "lane&15" index (A-row / B-col / D-col)
    const int lq   = lane >> 4;   // 0..3
    const int wr   = wave >> 1;   // row half owner (rows 32wr..32wr+31)
    const int wc   = wave & 1;    // channel/output half owner (64wc..64wc+63)

    const int bx    = blockIdx.x;
    const int n     = bx >> 3;
    const int chunk = bx & 7;
    const int l0c   = chunk * RPC;

    const float* xn = x + n * (MM * TT);

    // ---- preload weight fragments; biases go into the MFMA C operand ----
    bf16x8 w1f[4];                 // A1 = W1^T : [c][k], c = 64wc+16cf+lr, k>=9 zeroed
    bf16x8 w2f[4][4];              // A2 = W2^T : [o][i], o = 64wc+16of+lr, i = 32kk+8lq+e
    f32x4  b1f[4], b2f[4];         // bias in D-layout (row = lq*4+j)
    #pragma unroll
    for (int cf = 0; cf < 4; ++cf) {
        const int c = wc * 64 + cf * 16 + lr;
        bf16x8 a;
        #pragma unroll
        for (int e = 0; e < 8; ++e) {
            int k = lq * 8 + e;
            a[e] = (short)((k < 9) ? f2bf(w1[k * HH + c]) : (unsigned short)0);
        }
        w1f[cf] = a;
        #pragma unroll
        for (int kk = 0; kk < 4; ++kk) {
            bf16x8 wv;
            #pragma unroll
            for (int e = 0; e < 8; ++e)
                wv[e] = (short)f2bf(w2[(kk * 32 + lq * 8 + e) * HH + c]);
            w2f[cf][kk] = wv;
        }
        #pragma unroll
        for (int j = 0; j < 4; ++j) {
            b1f[cf][j] = b1[wc * 64 + cf * 16 + lq * 4 + j];
            b2f[cf][j] = b2[wc * 64 + cf * 16 + lq * 4 + j];
        }
    }

    // zero the xw tail row (row 256, read by lq=3 overread at r=255) once
    if (tid < XROW + 8) xw[XROW * RPH + tid] = 0;

    float colsum[4][4] = {{0,0,0,0},{0,0,0,0},{0,0,0,0},{0,0,0,0}};

    for (int half = 0; half < HALVES; ++half) {
        const int lbase = l0c + half * RPH;

        // ---- stage this half's 256 window-rows as bf16 ----
        // Safe: all xw reads (L1, before each step's barrier) of the previous
        // half are complete once every wave passed that half's last barrier.
        {
            const int r = tid;             // RPH == blockDim
            unsigned short kv[9];
            #pragma unroll
            for (int k = 0; k < 9; ++k) {  // k = i*3+m; coalesced over r per k
                const int i = k / 3;
                const int m = k - i * 3;
                const int t = lbase + r + i;
                kv[k] = (t < TT) ? f2bf(xn[m * TT + t]) : (unsigned short)0;
            }
            u16x4 s0, s1, s2;
            s0[0] = kv[0]; s0[1] = kv[1]; s0[2] = kv[2]; s0[3] = kv[3];
            s1[0] = kv[4]; s1[1] = kv[5]; s1[2] = kv[6]; s1[3] = kv[7];
            s2[0] = kv[8]; s2[1] = 0; s2[2] = 0; s2[3] = 0;
            u16x4 z; z[0] = 0; z[1] = 0; z[2] = 0; z[3] = 0;
            *(u16x4*)&xw[XROW * r]      = s0;
            *(u16x4*)&xw[XROW * r + 4]  = s1;
            *(u16x4*)&xw[XROW * r + 8]  = s2;
            *(u16x4*)&xw[XROW * r + 12] = z;
            *(u16x4*)&xw[XROW * r + 16] = z;
            *(u16x4*)&xw[XROW * r + 20] = z;
        }
        __syncthreads();   // staging visible to all waves

        for (int s = 0; s < STEPS; ++s) {
            const int buf = (half * STEPS + s) & 1;
            unsigned short* hb = &h1s[buf][0];

            // ---- layer 1: this wave's 32 rows x 64 channels (8 MFMA) ----
            bf16x8 bfr[2];
            #pragma unroll
            for (int rr = 0; rr < 2; ++rr) {
                const int R = s * SR + wr * 32 + rr * 16 + lr;   // row in half
                bfr[rr] = *(const bf16x8*)&xw[R * XROW + 8 * lq];
            }
            f32x4 acc1[4][2];
            #pragma unroll
            for (int cf = 0; cf < 4; ++cf)
                #pragma unroll
                for (int rr = 0; rr < 2; ++rr)
                    acc1[cf][rr] = __builtin_amdgcn_mfma_f32_16x16x32_bf16(
                                       w1f[cf], bfr[rr], b1f[cf], 0, 0, 0);

            // ---- relu + pack + swizzled store: h1s[r][c ^ ((r&15)<<3)] ----
            #pragma unroll
            for (int rr = 0; rr < 2; ++rr) {
                const int r   = wr * 32 + rr * 16 + lr;
                const int swz = lr << 3;                 // (r&15)<<3 == lr<<3
                #pragma unroll
                for (int cf = 0; cf < 4; ++cf) {
                    const int cb = wc * 64 + cf * 16 + lq * 4;
                    unsigned p0 = f2bf(fmaxf(acc1[cf][rr][0], 0.f));
                    unsigned p1 = f2bf(fmaxf(acc1[cf][rr][1], 0.f));
                    unsigned p2 = f2bf(fmaxf(acc1[cf][rr][2], 0.f));
                    unsigned p3 = f2bf(fmaxf(acc1[cf][rr][3], 0.f));
                    u32x2 pk;
                    pk[0] = p0 | (p1 << 16);
                    pk[1] = p2 | (p3 << 16);
                    *(u32x2*)&hb[r * HH + (cb ^ swz)] = pk;
                }
            }
            __syncthreads();   // h1 tile ready (dbuf removes the WAR barrier)

            // ---- layer 2: this wave's 32 rows x 64 outputs (32 MFMA) ----
            f32x4 acc2[4][2];
            #pragma unroll
            for (int rr = 0; rr < 2; ++rr) {
                const int r   = wr * 32 + rr * 16 + lr;
                const int swz = lr << 3;
                bf16x8 hf[4];
                #pragma unroll
                for (int kk = 0; kk < 4; ++kk)
                    hf[kk] = *(const bf16x8*)&hb[r * HH + ((kk * 32 + lq * 8) ^ swz)];
                #pragma unroll
                for (int of = 0; of < 4; ++of) {
                    acc2[of][rr] = __builtin_amdgcn_mfma_f32_16x16x32_bf16(
                                       w2f[of][0], hf[0], b2f[of], 0, 0, 0);
                    #pragma unroll
                    for (int kk = 1; kk < 4; ++kk)
                        acc2[of][rr] = __builtin_amdgcn_mfma_f32_16x16x32_bf16(
                                           w2f[of][kk], hf[kk], acc2[of][rr], 0, 0, 0);
                }
            }

            // ---- relu + column-sum; tail mask only on the affected frag ----
            const bool tailw = (chunk == CHUNKS - 1) && (half == HALVES - 1)
                               && (s == STEPS - 1) && (wr == 1);   // wave-uniform
            #pragma unroll
            for (int rr = 0; rr < 2; ++rr) {
                if (tailw && rr == 1) {           // rows 4078+16+lr; valid iff lr<14
                    const bool valid = lr < 14;
                    #pragma unroll
                    for (int of = 0; of < 4; ++of)
                        #pragma unroll
                        for (int j = 0; j < 4; ++j) {
                            float v = fmaxf(acc2[of][rr][j], 0.f);
                            if (valid) colsum[of][j] += v;
                        }
                } else {
                    #pragma unroll
                    for (int of = 0; of < 4; ++of)
                        #pragma unroll
                        for (int j = 0; j < 4; ++j)
                            colsum[of][j] += fmaxf(acc2[of][rr][j], 0.f);
                }
            }
        }
    }

    // ---- reduce colsum over 16 r-lanes, cross-wr add via LDS, write partial ----
    #pragma unroll
    for (int of = 0; of < 4; ++of)
        #pragma unroll
        for (int j = 0; j < 4; ++j) {
            float v = colsum[of][j];
            #pragma unroll
            for (int msk = 1; msk < 16; msk <<= 1)
                v += __shfl_xor(v, msk, 64);
            if (lr == 0)
                red[wr][wc * 64 + of * 16 + lq * 4 + j] = v;
        }
    __syncthreads();
    if (tid < HH)
        partials[(n * CHUNKS + chunk) * HH + tid] = red[0][tid] + red[1][tid];
}

// ---------------------------------------------------------------------------
// Kernel B: tail in fp32. inner = sum partials; oi = inner@W3 + L*b3;
// io = [x[:, :, :2] flat (6), oi]; g = relu(io@rw1+rb1); out = g@rw2+rb2.
// ---------------------------------------------------------------------------
__global__ __launch_bounds__(128) void pen_outer(
    const float* __restrict__ x,
    const float* __restrict__ w3, const float* __restrict__ b3,
    const float* __restrict__ rw1, const float* __restrict__ rb1,
    const float* __restrict__ rw2, const float* __restrict__ rb2,
    const float* __restrict__ partials,
    float* __restrict__ out)
{
    __shared__ float S[HH];
    __shared__ float IO[136];
    __shared__ float G[HH];
    const int n = blockIdx.x;
    const int c = threadIdx.x;

    float s = 0.f;
    #pragma unroll
    for (int ch = 0; ch < CHUNKS; ++ch)
        s += partials[(n * CHUNKS + ch) * HH + c];
    S[c] = s;
    if (c < 6) IO[c] = x[n * (MM * TT) + (c >> 1) * TT + (c & 1)];
    __syncthreads();

    float oi = (float)LL * b3[c];
    for (int k = 0; k < HH; ++k) oi += S[k] * w3[k * HH + c];
    IO[6 + c] = oi;
    __syncthreads();

    float g = rb1[c];
    for (int k = 0; k < 134; ++k) g += IO[k] * rw1[k * HH + c];
    G[c] = fmaxf(g, 0.f);
    __syncthreads();

    if (c < 10) {
        float o = rb2[c];
        for (int k = 0; k < HH; ++k) o += G[k] * rw2[k * 10 + c];
        out[n * 10 + c] = o;
    }
}

// ---------------------------------------------------------------------------
extern "C" void kernel_launch(void* const* d_in, const int* in_sizes, int n_in,
                              void* d_out, int out_size, void* d_ws, size_t ws_size,
                              hipStream_t stream)
{
    (void)in_sizes; (void)n_in; (void)out_size; (void)ws_size;
    const float* x   = (const float*)d_in[0];
    const float* w1  = (const float*)d_in[1];
    const float* b1  = (const float*)d_in[2];
    const float* w2  = (const float*)d_in[3];
    const float* b2  = (const float*)d_in[4];
    const float* w3  = (const float*)d_in[5];
    const float* b3  = (const float*)d_in[6];
    const float* rw1 = (const float*)d_in[7];
    const float* rb1 = (const float*)d_in[8];
    const float* rw2 = (const float*)d_in[9];
    const float* rb2 = (const float*)d_in[10];

    float* partials = (float*)d_ws;   // NN*CHUNKS*HH floats = 1 MiB of scratch

    pen_inner<<<NN * CHUNKS, 256, 0, stream>>>(x, w1, b1, w2, b2, partials);
    pen_outer<<<NN, 128, 0, stream>>>(x, w3, b3, rw1, rb1, rw2, rb2, partials,
                                      (float*)d_out);
}

// Round 7
// 88.652 us; speedup vs baseline: 1.0399x; 1.0399x over previous
//
#include <hip/hip_runtime.h>
#include <hip/hip_bf16.h>

// PartiallyExchangeableNetwork on MI355X (gfx950)
// N=256, M=3, T=4096, ORDER=2 -> L=4094 windows, H=128, OUT=10
//
// h1 = relu(xin @ W1 + b1); h2 = relu(h1 @ W2 + b2); colsum over L.
// Layer 3 folded through the sum: sum_l(h2@W3+b3) = (sum_l h2)@W3 + L*b3 (tail).
//
// R7: LDS-free inner pipeline. W1 channels are loaded PERMUTED
// (chan(cf,rho)=32(cf>>1)+8(rho>>2)+4(cf&1)+(rho&3)) so the L1 MFMA D-fragment
// pair (2kk,2kk+1), after relu+bf16-pack in registers, IS the L2 B-fragment
// for K-chunk kk (col=lr preserved, k=8lq+e matches). No h1 LDS, no per-step
// barriers; each wave owns independent 16-row units. b1 enters via a k=9
// ones-channel; b2 via the MFMA C operand. Waves split outputs 2-way
// (oh: 64 o each, W2^T frags = 64 VGPR), duplicating only L1 (8 MFMA/unit).

#define NN 256
#define MM 3
#define TT 4096
#define LL 4094
#define HH 128
#define CHUNKS 4           // 1024 rows per block
#define STAGES 4           // 4 stages of 256 rows
#define RPS 256            // rows per stage
#define XROW 24            // xw row stride in halfwords (48B, 2-way-free b128)

#define WS_W1 (512 * 1024)             // after 512KB partials
#define WS_W2 (512 * 1024 + 8192)      // w1 table = 512 frags * 16B

typedef __attribute__((ext_vector_type(8))) short bf16x8;
typedef __attribute__((ext_vector_type(4))) float f32x4;
typedef __attribute__((ext_vector_type(4))) unsigned short u16x4;
typedef __attribute__((ext_vector_type(4))) unsigned int u32x4;

__device__ __forceinline__ unsigned short f2bf(float x) {
    __hip_bfloat16 h = __float2bfloat16(x);           // RNE, hw cvt on gfx950
    union { __hip_bfloat16 h; unsigned short u; } v; v.h = h;
    return v.u;
}

// ---------------------------------------------------------------------------
// Prep: convert W1(+b1) and W2 into per-lane fragment tables in d_ws.
// w1t[cf][lane][e]: A-frag, row rho=lr -> channel chan(cf,lr), k=8lq+e
//                   (k<9: W1; k==9: b1; k>9: 0).
// w2t[oh][of][kk][lane][e]: A-frag, o = 64oh+16of+lr, i = 32kk+8lq+e.
// ---------------------------------------------------------------------------
__global__ void pen_prep(const float* __restrict__ w1, const float* __restrict__ b1,
                         const float* __restrict__ w2,
                         unsigned short* __restrict__ w1t,
                         unsigned short* __restrict__ w2t)
{
    const int tid = threadIdx.x;
    for (int idx = tid; idx < 512; idx += 256) {
        const int cf = idx >> 6, lane = idx & 63;
        const int lq = lane >> 4, lr = lane & 15;
        const int chan = 32 * (cf >> 1) + 8 * (lr >> 2) + 4 * (cf & 1) + (lr & 3);
        #pragma unroll
        for (int e = 0; e < 8; ++e) {
            const int k = 8 * lq + e;
            float v = 0.f;
            if (k < 9)       v = w1[k * HH + chan];
            else if (k == 9) v = b1[chan];
            w1t[idx * 8 + e] = f2bf(v);
        }
    }
    for (int idx = tid; idx < 2048; idx += 256) {
        const int lane = idx & 63;
        const int kk = (idx >> 6) & 3, of = (idx >> 8) & 3, oh = idx >> 10;
        const int lq = lane >> 4, lr = lane & 15;
        const int o = oh * 64 + of * 16 + lr;
        #pragma unroll
        for (int e = 0; e < 8; ++e) {
            const int i = 32 * kk + 8 * lq + e;
            w2t[idx * 8 + e] = f2bf(w2[i * HH + o]);
        }
    }
}

// ---------------------------------------------------------------------------
// Kernel A: block = (n, chunk of 1024 rows); 4 stages of 256 rows.
// Wave (rg,oh): units u = 2uu+rg (16 rows each), outputs [64oh, 64oh+64).
// ---------------------------------------------------------------------------
__global__ __launch_bounds__(256, 2) void pen_inner(
    const float* __restrict__ x,
    const float* __restrict__ b2,
    const unsigned short* __restrict__ w1t,
    const unsigned short* __restrict__ w2t,
    float* __restrict__ partials)
{
    __shared__ __align__(16) unsigned short xw[XROW * RPS + 32];  // 12.4 KB
    __shared__ float red[2][HH];                                  // 1 KB

    const int tid  = threadIdx.x;
    const int wave = tid >> 6;
    const int lane = tid & 63;
    const int lr   = lane & 15;
    const int lq   = lane >> 4;
    const int rg   = wave >> 1;    // row-group owner (units 2uu+rg)
    const int oh   = wave & 1;     // output half [64oh, 64oh+64)

    const int bx    = blockIdx.x;
    const int n     = bx >> 2;
    const int chunk = bx & 3;

    const float* xn = x + n * (MM * TT);

    // ---- load fragment tables (coalesced b128 per lane) ----
    bf16x8 w1f[8];
    #pragma unroll
    for (int cf = 0; cf < 8; ++cf)
        w1f[cf] = *(const bf16x8*)&w1t[(cf * 64 + lane) * 8];
    bf16x8 w2f[4][4];
    #pragma unroll
    for (int of = 0; of < 4; ++of)
        #pragma unroll
        for (int kk = 0; kk < 4; ++kk)
            w2f[of][kk] = *(const bf16x8*)&w2t[(((oh * 4 + of) * 4 + kk) * 64 + lane) * 8];
    f32x4 b2f[4];
    #pragma unroll
    for (int of = 0; of < 4; ++of)
        #pragma unroll
        for (int j = 0; j < 4; ++j)
            b2f[of][j] = b2[oh * 64 + of * 16 + lq * 4 + j];

    if (tid < 32) xw[XROW * RPS + tid] = 0;   // pad row (lq=3 overread at r=255)

    const f32x4 zero4 = {0.f, 0.f, 0.f, 0.f};
    const int xo = XROW * lr + 8 * lq;        // per-lane xw read offset (hw)
    float colsum[4][4] = {{0,0,0,0},{0,0,0,0},{0,0,0,0},{0,0,0,0}};

    for (int st = 0; st < STAGES; ++st) {
        __syncthreads();   // prev stage's xw reads complete

        // ---- stage 256 window-rows as bf16; k=9 slot = 1.0 (bias channel) ----
        {
            const int r = tid;                 // RPS == blockDim
            const int rowg = chunk * 1024 + st * 256 + r;
            unsigned short kv[9];
            #pragma unroll
            for (int k = 0; k < 9; ++k) {      // k = i*3+m; coalesced over r per k
                const int i = k / 3;
                const int m = k - i * 3;
                const int t = rowg + i;
                kv[k] = (t < TT) ? f2bf(xn[m * TT + t]) : (unsigned short)0;
            }
            u16x4 s0, s1, s2;
            s0[0] = kv[0]; s0[1] = kv[1]; s0[2] = kv[2]; s0[3] = kv[3];
            s1[0] = kv[4]; s1[1] = kv[5]; s1[2] = kv[6]; s1[3] = kv[7];
            s2[0] = kv[8]; s2[1] = 0x3F80; s2[2] = 0; s2[3] = 0;   // 1.0 at k=9
            u16x4 z; z[0] = 0; z[1] = 0; z[2] = 0; z[3] = 0;
            *(u16x4*)&xw[XROW * r]      = s0;
            *(u16x4*)&xw[XROW * r + 4]  = s1;
            *(u16x4*)&xw[XROW * r + 8]  = s2;
            *(u16x4*)&xw[XROW * r + 12] = z;
            *(u16x4*)&xw[XROW * r + 16] = z;
            *(u16x4*)&xw[XROW * r + 20] = z;
        }
        __syncthreads();   // staging visible

        // ---- 8 independent 16-row units per wave, no barriers ----
        #pragma unroll 2
        for (int uu = 0; uu < 8; ++uu) {
            const int u = uu * 2 + rg;
            const bf16x8 bfrag = *(const bf16x8*)&xw[u * (XROW * 16) + xo];

            // L1: permuted channels, bias via k=9 ones-channel
            f32x4 acc1[8];
            #pragma unroll
            for (int cf = 0; cf < 8; ++cf)
                acc1[cf] = __builtin_amdgcn_mfma_f32_16x16x32_bf16(
                               w1f[cf], bfrag, zero4, 0, 0, 0);

            // relu + pack: D-frag pair (2kk,2kk+1) -> L2 B-frag for chunk kk
            bf16x8 pa[4];
            #pragma unroll
            for (int kk = 0; kk < 4; ++kk) {
                u32x4 d;
                d[0] = (unsigned)f2bf(fmaxf(acc1[2*kk][0], 0.f))
                     | ((unsigned)f2bf(fmaxf(acc1[2*kk][1], 0.f)) << 16);
                d[1] = (unsigned)f2bf(fmaxf(acc1[2*kk][2], 0.f))
                     | ((unsigned)f2bf(fmaxf(acc1[2*kk][3], 0.f)) << 16);
                d[2] = (unsigned)f2bf(fmaxf(acc1[2*kk+1][0], 0.f))
                     | ((unsigned)f2bf(fmaxf(acc1[2*kk+1][1], 0.f)) << 16);
                d[3] = (unsigned)f2bf(fmaxf(acc1[2*kk+1][2], 0.f))
                     | ((unsigned)f2bf(fmaxf(acc1[2*kk+1][3], 0.f)) << 16);
                pa[kk] = __builtin_bit_cast(bf16x8, d);
            }

            // L2: 64 outputs x 16 rows, K=128; b2 via C operand
            f32x4 acc2[4];
            #pragma unroll
            for (int of = 0; of < 4; ++of)
                acc2[of] = __builtin_amdgcn_mfma_f32_16x16x32_bf16(
                               w2f[of][0], pa[0], b2f[of], 0, 0, 0);
            #pragma unroll
            for (int kk = 1; kk < 4; ++kk)
                #pragma unroll
                for (int of = 0; of < 4; ++of)
                    acc2[of] = __builtin_amdgcn_mfma_f32_16x16x32_bf16(
                                   w2f[of][kk], pa[kk], acc2[of], 0, 0, 0);

            // relu + column-sum (rows = cols lr); mask only the global tail
            if ((chunk == 3) && (st == 3) && (uu == 7) && (rg == 1)) {
                const bool valid = lr < 14;        // rows 4080+lr < 4094
                #pragma unroll
                for (int of = 0; of < 4; ++of)
                    #pragma unroll
                    for (int j = 0; j < 4; ++j) {
                        float v = fmaxf(acc2[of][j], 0.f);
                        if (valid) colsum[of][j] += v;
                    }
            } else {
                #pragma unroll
                for (int of = 0; of < 4; ++of)
                    #pragma unroll
                    for (int j = 0; j < 4; ++j)
                        colsum[of][j] += fmaxf(acc2[of][j], 0.f);
            }
        }
    }

    // ---- reduce over 16 col-lanes, cross-rg add via LDS, write partial ----
    #pragma unroll
    for (int of = 0; of < 4; ++of)
        #pragma unroll
        for (int j = 0; j < 4; ++j) {
            float v = colsum[of][j];
            #pragma unroll
            for (int msk = 1; msk < 16; msk <<= 1)
                v += __shfl_xor(v, msk, 64);
            if (lr == 0)
                red[rg][oh * 64 + of * 16 + lq * 4 + j] = v;
        }
    __syncthreads();
    if (tid < HH)
        partials[(n * CHUNKS + chunk) * HH + tid] = red[0][tid] + red[1][tid];
}

// ---------------------------------------------------------------------------
// Kernel B: tail in fp32. inner = sum partials; oi = inner@W3 + L*b3;
// io = [x[:, :, :2] flat (6), oi]; g = relu(io@rw1+rb1); out = g@rw2+rb2.
// ---------------------------------------------------------------------------
__global__ __launch_bounds__(128) void pen_outer(
    const float* __restrict__ x,
    const float* __restrict__ w3, const float* __restrict__ b3,
    const float* __restrict__ rw1, const float* __restrict__ rb1,
    const float* __restrict__ rw2, const float* __restrict__ rb2,
    const float* __restrict__ partials,
    float* __restrict__ out)
{
    __shared__ float S[HH];
    __shared__ float IO[136];
    __shared__ float G[HH];
    const int n = blockIdx.x;
    const int c = threadIdx.x;

    float s = 0.f;
    #pragma unroll
    for (int ch = 0; ch < CHUNKS; ++ch)
        s += partials[(n * CHUNKS + ch) * HH + c];
    S[c] = s;
    if (c < 6) IO[c] = x[n * (MM * TT) + (c >> 1) * TT + (c & 1)];
    __syncthreads();

    float oi = (float)LL * b3[c];
    for (int k = 0; k < HH; ++k) oi += S[k] * w3[k * HH + c];
    IO[6 + c] = oi;
    __syncthreads();

    float g = rb1[c];
    for (int k = 0; k < 134; ++k) g += IO[k] * rw1[k * HH + c];
    G[c] = fmaxf(g, 0.f);
    __syncthreads();

    if (c < 10) {
        float o = rb2[c];
        for (int k = 0; k < HH; ++k) o += G[k] * rw2[k * 10 + c];
        out[n * 10 + c] = o;
    }
}

// ---------------------------------------------------------------------------
extern "C" void kernel_launch(void* const* d_in, const int* in_sizes, int n_in,
                              void* d_out, int out_size, void* d_ws, size_t ws_size,
                              hipStream_t stream)
{
    (void)in_sizes; (void)n_in; (void)out_size; (void)ws_size;
    const float* x   = (const float*)d_in[0];
    const float* w1  = (const float*)d_in[1];
    const float* b1  = (const float*)d_in[2];
    const float* w2  = (const float*)d_in[3];
    const float* b2  = (const float*)d_in[4];
    const float* w3  = (const float*)d_in[5];
    const float* b3  = (const float*)d_in[6];
    const float* rw1 = (const float*)d_in[7];
    const float* rb1 = (const float*)d_in[8];
    const float* rw2 = (const float*)d_in[9];
    const float* rb2 = (const float*)d_in[10];

    float*          partials = (float*)d_ws;                            // 512 KB
    unsigned short* w1t = (unsigned short*)((char*)d_ws + WS_W1);       // 8 KB
    unsigned short* w2t = (unsigned short*)((char*)d_ws + WS_W2);       // 32 KB

    pen_prep<<<1, 256, 0, stream>>>(w1, b1, w2, w1t, w2t);
    pen_inner<<<NN * CHUNKS, 256, 0, stream>>>(x, b2, w1t, w2t, partials);
    pen_outer<<<NN, 128, 0, stream>>>(x, w3, b3, rw1, rb1, rw2, rb2, partials,
                                      (float*)d_out);
}